// Round 1
// baseline (1347.676 us; speedup 1.0000x reference)
//
#include <hip/hip_runtime.h>
#include <hip/hip_bf16.h>

// BlockLinear: y[b,o] = sum_{k<16} x[b, o*16+k] * w[o,k]
// B=8192, IN=32768, OUT=2048, BLOCK=16, fp32 in/out.
// Memory-bound: ~1.14 GB traffic -> ~181 us floor @ 6.3 TB/s.
// Since IN == OUT*BLOCK, flat x offset for output idx = b*OUT + o is idx*16:
// each thread owns a contiguous 64B slice of x (4x float4), dots with 64B of
// weight (L2-resident, reused by all 8192 rows), writes one coalesced float.

#define OUT_F 2048
#define TOTAL_OUT (8192LL * 2048LL)

__global__ __launch_bounds__(256) void blocklinear_kernel(
    const float* __restrict__ x,
    const float* __restrict__ w,
    float* __restrict__ y) {
  const long long idx = (long long)blockIdx.x * 256 + threadIdx.x;  // b*OUT + o
  const int o = (int)(idx & (OUT_F - 1));

  const float4* __restrict__ xv = reinterpret_cast<const float4*>(x) + idx * 4;
  const float4* __restrict__ wv = reinterpret_cast<const float4*>(w) + (long long)o * 4;

  float4 a0 = xv[0];
  float4 a1 = xv[1];
  float4 a2 = xv[2];
  float4 a3 = xv[3];
  float4 b0 = wv[0];
  float4 b1 = wv[1];
  float4 b2 = wv[2];
  float4 b3 = wv[3];

  float s = a0.x * b0.x + a0.y * b0.y + a0.z * b0.z + a0.w * b0.w;
  s += a1.x * b1.x + a1.y * b1.y + a1.z * b1.z + a1.w * b1.w;
  s += a2.x * b2.x + a2.y * b2.y + a2.z * b2.z + a2.w * b2.w;
  s += a3.x * b3.x + a3.y * b3.y + a3.z * b3.z + a3.w * b3.w;

  y[idx] = s;
}

extern "C" void kernel_launch(void* const* d_in, const int* in_sizes, int n_in,
                              void* d_out, int out_size, void* d_ws, size_t ws_size,
                              hipStream_t stream) {
  const float* x = (const float*)d_in[0];   // (8192, 32768) fp32
  const float* w = (const float*)d_in[1];   // (2048, 16) fp32
  float* y = (float*)d_out;                 // (8192, 2048) fp32

  const long long total = TOTAL_OUT;        // 16,777,216 — exact multiple of 256
  dim3 grid((unsigned)(total / 256));
  dim3 block(256);
  hipLaunchKernelGGL(blocklinear_kernel, grid, block, 0, stream, x, w, y);
}